// Round 4
// baseline (1894.892 us; speedup 1.0000x reference)
//
#include <hip/hip_runtime.h>
#include <hip/hip_bf16.h>
#include <math.h>

#define DD   4096   // feature dim
#define HH   2048   // hidden dim
#define NE   64     // experts
#define BK   32
#define NT   16     // hidden tiles (HH/128)
#define GM   32     // gate token tile

typedef __attribute__((ext_vector_type(8))) short bf16x8;
typedef __attribute__((ext_vector_type(4))) float f32x4;

// async global->LDS, 16B per lane, dest = uniform base + lane*16
__device__ __forceinline__ void async16(void* lds, const void* g) {
    __builtin_amdgcn_global_load_lds(
        (const __attribute__((address_space(1))) unsigned int*)g,
        (__attribute__((address_space(3))) unsigned int*)lds, 16, 0, 0);
}

// split two floats into bf16 hi (RNE) + bf16 lo (RNE of exact residual)
__device__ __forceinline__ void split2(float a, float b, unsigned& hi, unsigned& lo) {
    __hip_bfloat162 h = __float22bfloat162_rn(make_float2(a, b));
    float2 hf = __bfloat1622float2(h);
    __hip_bfloat162 l = __float22bfloat162_rn(make_float2(a - hf.x, b - hf.y));
    __builtin_memcpy(&hi, &h, 4);
    __builtin_memcpy(&lo, &l, 4);
}

// ---------------------------------------------------------------------------
// presplit x -> hi/lo bf16 planes in MFMA FRAGMENT order:
//   chunk index = ((mt*128 + ks)*8 + fb)*64 + ln   (16B uint4 chunks)
//   holds x[row = mt*128 + fb*16 + (ln&15)][k = ks*32 + (ln>>4)*8 .. +8]
// ---------------------------------------------------------------------------
__global__ __launch_bounds__(256) void split_xf(
    const float* __restrict__ x, uint4* __restrict__ xfh, uint4* __restrict__ xfl)
{
    const int t = threadIdx.x;
    const int mt = blockIdx.x >> 7;      // token tile (128 rows)
    const int ks = blockIdx.x & 127;     // k step (32 k)
#pragma unroll
    for (int s2 = 0; s2 < 2; ++s2) {
        int s = t + s2 * 256;            // 0..511 chunk within (mt,ks)
        int fb = s >> 6, ln = s & 63;
        int row = mt * 128 + fb * 16 + (ln & 15);
        int k   = ks * 32 + (ln >> 4) * 8;
        const float* g = x + (size_t)row * DD + k;
        float4 a = *(const float4*)g, b = *(const float4*)(g + 4);
        unsigned h0, l0, h1, l1, h2, l2, h3, l3;
        split2(a.x, a.y, h0, l0); split2(a.z, a.w, h1, l1);
        split2(b.x, b.y, h2, l2); split2(b.z, b.w, h3, l3);
        size_t idx = ((size_t)blockIdx.x * 8 + fb) * 64 + ln;
        xfh[idx] = make_uint4(h0, h1, h2, h3);
        xfl[idx] = make_uint4(l0, l1, l2, l3);
    }
}

// ---------------------------------------------------------------------------
// presplit + transpose W1[K][N] -> W1t hi/lo planes [N][K]
// ---------------------------------------------------------------------------
__global__ __launch_bounds__(256) void split_w1t(
    const float* __restrict__ W1,
    unsigned short* __restrict__ th, unsigned short* __restrict__ tl)
{
    __shared__ float ts[32][33];
    const int n0 = blockIdx.x * 32, k0 = blockIdx.y * 32;
    const int t = threadIdx.x;
    {
        int r = t >> 3, c4 = (t & 7) * 4;
        float4 v = *(const float4*)&W1[(size_t)(k0 + r) * HH + n0 + c4];
        ts[r][c4] = v.x; ts[r][c4 + 1] = v.y; ts[r][c4 + 2] = v.z; ts[r][c4 + 3] = v.w;
    }
    __syncthreads();
    int n = t >> 3, kk = (t & 7) * 4;
    float f0 = ts[kk][n], f1 = ts[kk + 1][n], f2 = ts[kk + 2][n], f3 = ts[kk + 3][n];
    unsigned h0, l0, h1, l1;
    split2(f0, f1, h0, l0); split2(f2, f3, h1, l1);
    *(uint2*)&th[(size_t)(n0 + n) * DD + k0 + kk] = make_uint2(h0, h1);
    *(uint2*)&tl[(size_t)(n0 + n) * DD + k0 + kk] = make_uint2(l0, l1);
}

// ---------------------------------------------------------------------------
// K1: predictor GEMM via bf16 MFMA, 3-product hi/lo split, fp32 MFMA acc.
// 128x128 tile, BK=32. A operands direct global->VGPR from fragment-ordered
// planes. NEW this round:
//  - B LDS double-buffered (2 x 16KB) -> ONE barrier per K-step; B asyncs
//    for ks+1 issued at the top of step ks (cover = full step).
//  - A-lo ping-pong registers (alA/alB, static via 2-step unroll): the
//    al(ks+1) load is issued at the TOP of step ks, giving it a full-step
//    (~2000 cyc) cover instead of ZERO (it previously issued right before
//    the barrier's vmcnt(0) drain -> ate ~900 cyc HBM latency every step).
//  - ah reload stays right after its last use (pass1); cover = pass2 +
//    next step's frag reads.
// MFMA product order per acc element stays hh -> hl -> lh => pl bitwise
// identical to previous rounds.
// ---------------------------------------------------------------------------
template<bool PRE_A>
__global__ __launch_bounds__(256, 3) void pred_mfma(
    const float* __restrict__ x,
    const unsigned short* __restrict__ xh, const unsigned short* __restrict__ xl,
    const unsigned short* __restrict__ w1th, const unsigned short* __restrict__ w1tl,
    const float* __restrict__ b1, const float* __restrict__ W2,
    double* __restrict__ pl)
{
    __shared__ __align__(16) char lds[32768];

    const int t = threadIdx.x, wv = t >> 6, ln = t & 63;
    // XCD swizzle: consecutive lins hit distinct XCDs; ntile fast within mtile
    const int lin = blockIdx.x;
    const int sub = lin >> 3;
    const int ntile = (lin & 7) * 2 + (sub & 1);
    const int mtile = sub >> 1;
    const int m0 = mtile * 128, n0 = ntile * 128;
    const int frow = ln & 15;            // fragment row/col within 16
    const int fkb  = (ln >> 4) * 8;      // fragment k offset (8 bf16)

    f32x4 acc[4][4];
#pragma unroll
    for (int i = 0; i < 4; ++i)
#pragma unroll
        for (int j = 0; j < 4; ++j) acc[i][j] = (f32x4){0.f, 0.f, 0.f, 0.f};

    const int mb = (wv & 1) * 4, nb = (wv >> 1) * 4;

    if (PRE_A) {
        // buffer b (0/1) base: lds + b*16384; within buffer: Bh +0, Bl +8192
        // staging role: wv0 -> Bh fb0-3, wv1 -> Bh fb4-7,
        //               wv2 -> Bl fb0-3, wv3 -> Bl fb4-7
        const unsigned short* bsrc = (wv & 2) ? w1tl : w1th;
        const int roleoff = ((wv & 2) ? 8192 : 0) + (wv & 1) * 4096;
        const unsigned short* bg =
            bsrc + (size_t)(n0 + (wv & 1) * 64 + frow) * DD + fkb;

        // A fragment-plane per-lane bases (uint4 units); frag i of step ks is
        // at base + ks*512 + i*64
        const uint4* gh = (const uint4*)xh + ((size_t)mtile * 1024 + mb) * 64 + ln;
        const uint4* gl = (const uint4*)xl + ((size_t)mtile * 1024 + mb) * 64 + ln;

        bf16x8 ah[4], alA[4], alB[4];

        // prologue: stage B(0) -> buf0, load ah(0), alA(0)
#pragma unroll
        for (int q = 0; q < 4; ++q)
            async16(lds + roleoff + q * 1024, bg + (size_t)q * 16 * DD);
#pragma unroll
        for (int i = 0; i < 4; ++i) {
            ah[i]  = *(const bf16x8*)(gh + i * 64);
            alA[i] = *(const bf16x8*)(gl + i * 64);
        }

        // one step; RB = read buffer base, SB = stage buffer base (chars)
        // alC = current A-lo regs, alN = next A-lo regs
#define PRED_STEP(KS, RBOFF, SBOFF, alC, alN)                                  \
        {                                                                      \
            __syncthreads(); /* vmcnt(0): drains B(KS) asyncs + A(KS) loads */ \
            const bool more = (KS) + 1 < 128;                                  \
            if (more) {                                                        \
                /* al(KS+1): longest-latency load, issue first */              \
                _Pragma("unroll")                                              \
                for (int i = 0; i < 4; ++i)                                    \
                    alN[i] = *(const bf16x8*)(gh_l + (size_t)((KS)+1) * 512 + i * 64); \
                /* B(KS+1) asyncs into the other buffer */                     \
                _Pragma("unroll")                                              \
                for (int q = 0; q < 4; ++q)                                    \
                    async16(lds + (SBOFF) + roleoff + q * 1024,                \
                            bg + (size_t)q * 16 * DD + ((KS)+1) * BK);         \
            }                                                                  \
            bf16x8 bfh[4], bfl[4];                                             \
            _Pragma("unroll")                                                  \
            for (int j = 0; j < 4; ++j) {                                      \
                bfh[j] = *(const bf16x8*)(lds + (RBOFF) + (nb + j) * 1024 + ln * 16);        \
                bfl[j] = *(const bf16x8*)(lds + (RBOFF) + 8192 + (nb + j) * 1024 + ln * 16); \
            }                                                                  \
            /* pass 1: hh + hl (last use of ah) */                             \
            _Pragma("unroll")                                                  \
            for (int i = 0; i < 4; ++i)                                        \
                _Pragma("unroll")                                              \
                for (int j = 0; j < 4; ++j) {                                  \
                    acc[i][j] = __builtin_amdgcn_mfma_f32_16x16x32_bf16(ah[i], bfh[j], acc[i][j], 0, 0, 0); \
                    acc[i][j] = __builtin_amdgcn_mfma_f32_16x16x32_bf16(ah[i], bfl[j], acc[i][j], 0, 0, 0); \
                }                                                              \
            if (more) {                                                        \
                _Pragma("unroll")                                              \
                for (int i = 0; i < 4; ++i)                                    \
                    ah[i] = *(const bf16x8*)(gh + (size_t)((KS)+1) * 512 + i * 64); \
            }                                                                  \
            /* pass 2: lh (uses current A-lo) */                               \
            _Pragma("unroll")                                                  \
            for (int i = 0; i < 4; ++i)                                        \
                _Pragma("unroll")                                              \
                for (int j = 0; j < 4; ++j)                                    \
                    acc[i][j] = __builtin_amdgcn_mfma_f32_16x16x32_bf16(alC[i], bfh[j], acc[i][j], 0, 0, 0); \
        }

        const uint4* gh_l = gl;   // alias used inside the macro for al loads
        for (int ks = 0; ks < 128; ks += 2) {
            PRED_STEP(ks,     0,     16384, alA, alB);
            PRED_STEP(ks + 1, 16384, 0,     alB, alA);
        }
#undef PRED_STEP
    } else {
        // fallback: in-kernel split of fp32 x (round-0 structure, unchanged)
        char* Ah = lds;
        char* Al = lds + 8192;
        char* Bh = lds + 16384;
        char* Bl = lds + 24576;
        const unsigned short* gBh = w1th + (size_t)(n0 + frow) * DD + fkb;
        const unsigned short* gBl = w1tl + (size_t)(n0 + frow) * DD + fkb;

        for (int kc = 0; kc < DD; kc += BK) {
#pragma unroll
            for (int q = 0; q < 2; ++q) {
                int fb = wv * 2 + q;
                async16(Bh + fb * 1024, gBh + (size_t)fb * 16 * DD + kc);
                async16(Bl + fb * 1024, gBl + (size_t)fb * 16 * DD + kc);
            }
#pragma unroll
            for (int s2 = 0; s2 < 2; ++s2) {
                int s = t + s2 * 256;
                int fb = s >> 6, sl = s & 63;
                int row = fb * 16 + (sl & 15), kb = (sl >> 4) * 8;
                const float* g = x + (size_t)(m0 + row) * DD + kc + kb;
                float4 a = *(const float4*)g, b = *(const float4*)(g + 4);
                unsigned h0, l0, h1, l1, h2, l2, h3, l3;
                split2(a.x, a.y, h0, l0); split2(a.z, a.w, h1, l1);
                split2(b.x, b.y, h2, l2); split2(b.z, b.w, h3, l3);
                *(uint4*)(Ah + s * 16) = make_uint4(h0, h1, h2, h3);
                *(uint4*)(Al + s * 16) = make_uint4(l0, l1, l2, l3);
            }
            __syncthreads();

            bf16x8 afh[4], afl[4], bfh[4], bfl[4];
#pragma unroll
            for (int i = 0; i < 4; ++i) {
                afh[i] = *(const bf16x8*)(Ah + (mb + i) * 1024 + ln * 16);
                afl[i] = *(const bf16x8*)(Al + (mb + i) * 1024 + ln * 16);
                bfh[i] = *(const bf16x8*)(Bh + (nb + i) * 1024 + ln * 16);
                bfl[i] = *(const bf16x8*)(Bl + (nb + i) * 1024 + ln * 16);
            }
#pragma unroll
            for (int i = 0; i < 4; ++i)
#pragma unroll
                for (int j = 0; j < 4; ++j) {
                    acc[i][j] = __builtin_amdgcn_mfma_f32_16x16x32_bf16(afh[i], bfh[j], acc[i][j], 0, 0, 0);
                    acc[i][j] = __builtin_amdgcn_mfma_f32_16x16x32_bf16(afh[i], bfl[j], acc[i][j], 0, 0, 0);
                    acc[i][j] = __builtin_amdgcn_mfma_f32_16x16x32_bf16(afl[i], bfh[j], acc[i][j], 0, 0, 0);
                }
            __syncthreads();
        }
    }

    // epilogue: relu(c + b1) * W2, fp64 reduction. C layout: col=ln&15,
    // row=(ln>>4)*4+r per 16x16 frag.
    __syncthreads();
    double* redd = (double*)lds;   // [2][128]
    const int mh = wv & 1, nh = wv >> 1;
    float b1v[4], w2v[4];
#pragma unroll
    for (int j = 0; j < 4; ++j) {
        int col = n0 + nh * 64 + j * 16 + frow;
        b1v[j] = b1[col];
        w2v[j] = W2[col];
    }
#pragma unroll
    for (int i = 0; i < 4; ++i)
#pragma unroll
        for (int r = 0; r < 4; ++r) {
            double s = 0.0;
#pragma unroll
            for (int j = 0; j < 4; ++j) {
                float h = acc[i][j][r] + b1v[j];
                h = fmaxf(h, 0.f);
                s += (double)h * (double)w2v[j];
            }
#pragma unroll
            for (int o = 1; o < 16; o <<= 1) s += __shfl_xor(s, o, 64);
            if (frow == 0)
                redd[nh * 128 + mh * 64 + i * 16 + (ln >> 4) * 4 + r] = s;
        }
    __syncthreads();
    if (t < 128)
        pl[(size_t)(m0 + t) * NT + ntile] = redd[t] + redd[128 + t];
}

// ---------------------------------------------------------------------------
// Fallback K1 (round-2): fp32 VALU GEMM, used only if ws is too small.
// ---------------------------------------------------------------------------
__global__ __launch_bounds__(256) void pred_gemm(
    const float* __restrict__ x, const float* __restrict__ W1,
    const float* __restrict__ b1, const float* __restrict__ W2,
    double* __restrict__ pl)
{
    __shared__ float As[BK][128];
    __shared__ float Bs[BK][128];
    __shared__ double red[128][NT + 1];

    const int ht = blockIdx.x;
    const int tm = blockIdx.y;
    const int t  = threadIdx.x;
    const int tx = t & 15, ty = t >> 4;
    const int h0 = ht * 128;
    const int m0 = tm * 128;

    float acc[8][8];
#pragma unroll
    for (int i = 0; i < 8; ++i)
#pragma unroll
        for (int j = 0; j < 8; ++j) acc[i][j] = 0.f;

    const int arow = t >> 1, acol = (t & 1) << 4;
    const int brow = t >> 3, bcol = (t & 7) << 4;
    const float* xrow = x  + (size_t)(m0 + arow) * DD + acol;
    const float* wrow = W1 + (size_t)brow * HH + h0 + bcol;

    for (int k0 = 0; k0 < DD; k0 += BK) {
        float4 a4[4], b4[4];
        const float4* ap = (const float4*)(xrow + k0);
#pragma unroll
        for (int i = 0; i < 4; ++i) a4[i] = ap[i];
        const float4* bp = (const float4*)(wrow + (size_t)k0 * HH);
#pragma unroll
        for (int i = 0; i < 4; ++i) b4[i] = bp[i];
        __syncthreads();
#pragma unroll
        for (int i = 0; i < 4; ++i) {
            As[acol + i * 4 + 0][arow] = a4[i].x;
            As[acol + i * 4 + 1][arow] = a4[i].y;
            As[acol + i * 4 + 2][arow] = a4[i].z;
            As[acol + i * 4 + 3][arow] = a4[i].w;
        }
#pragma unroll
        for (int i = 0; i < 4; ++i)
            *(float4*)&Bs[brow][bcol + i * 4] = b4[i];
        __syncthreads();
#pragma unroll 8
        for (int kk = 0; kk < BK; ++kk) {
            float4 a0  = *(const float4*)&As[kk][ty * 8];
            float4 a1  = *(const float4*)&As[kk][ty * 8 + 4];
            float4 bb0 = *(const float4*)&Bs[kk][tx * 8];
            float4 bb1 = *(const float4*)&Bs[kk][tx * 8 + 4];
            float av[8] = {a0.x, a0.y, a0.z, a0.w, a1.x, a1.y, a1.z, a1.w};
            float bv[8] = {bb0.x, bb0.y, bb0.z, bb0.w, bb1.x, bb1.y, bb1.z, bb1.w};
#pragma unroll
            for (int i = 0; i < 8; ++i)
#pragma unroll
                for (int j = 0; j < 8; ++j)
                    acc[i][j] = fmaf(av[i], bv[j], acc[i][j]);
        }
    }
    __syncthreads();
#pragma unroll
    for (int r = 0; r < 8; ++r) {
        double s = 0.0;
#pragma unroll
        for (int c = 0; c < 8; ++c) {
            int h = h0 + tx * 8 + c;
            float v = acc[r][c] + b1[h];
            v = v > 0.f ? v : 0.f;
            s += (double)v * (double)W2[h];
        }
        red[ty * 8 + r][tx] = s;
    }
    __syncthreads();
    if (t < 128) {
        double s = 0.0;
#pragma unroll
        for (int j = 0; j < NT; ++j) s += red[t][j];
        pl[(size_t)(m0 + t) * NT + ht] = s;
    }
}

// ---------------------------------------------------------------------------
// K2 (fused): fp64 gating GEMM + routing epilogue.
// Round-0 version RESTORED VERBATIM (fastest measured): 256 thr, 2x4 tile,
// 32-token blocks, fp32 LDS tiles, register prefetch of next K-chunk.
// ---------------------------------------------------------------------------
__global__ __launch_bounds__(256) void gate_fused(
    const float* __restrict__ x, const float* __restrict__ W,
    const double* __restrict__ pl, const float* __restrict__ b2,
    float* __restrict__ out, int Ntok)
{
    __shared__ __align__(16) char smem[GM * (NE + 1) * sizeof(double)]; // 16.6 KB
    float (*As)[GM] = (float(*)[GM])smem;                  // [BK][GM]  4 KB
    float (*Bs)[NE] = (float(*)[NE])(smem + BK * GM * 4);  // [BK][NE]  8 KB
    double (*Dm)[NE + 1] = (double(*)[NE + 1])smem;        // logits after GEMM

    const int tm = blockIdx.x;
    const int t  = threadIdx.x;
    const int tx = t & 15, ty = t >> 4;    // output: rows ty*2..+1, cols tx*4..+3
    const int m0 = tm * GM;

    double acc[2][4];
#pragma unroll
    for (int i = 0; i < 2; ++i)
#pragma unroll
        for (int j = 0; j < 4; ++j) acc[i][j] = 0.0;

    const int arow = t >> 3, acol = (t & 7) * 4;   // A: 32 rows x 32 k, 1 float4/thr
    const int brow = t >> 3, bcol = (t & 7) * 8;   // B: 32 k x 64,     2 float4/thr
    const float* xrow = x + (size_t)(m0 + arow) * DD + acol;
    const float* wrow = W + (size_t)brow * NE + bcol;

    // prologue: chunk-0 registers
    float4 a4  = *(const float4*)xrow;
    float4 b40 = *(const float4*)wrow;
    float4 b41 = *(const float4*)(wrow + 4);

    for (int k0 = 0; k0 < DD; k0 += BK) {
        __syncthreads();                 // previous compute done reading LDS
        As[acol + 0][arow] = a4.x;       // A transpose to k-major
        As[acol + 1][arow] = a4.y;
        As[acol + 2][arow] = a4.z;
        As[acol + 3][arow] = a4.w;
        *(float4*)&Bs[brow][bcol]     = b40;
        *(float4*)&Bs[brow][bcol + 4] = b41;
        __syncthreads();

        if (k0 + BK < DD) {              // prefetch next chunk into registers
            a4  = *(const float4*)(xrow + k0 + BK);
            b40 = *(const float4*)(wrow + (size_t)(k0 + BK) * NE);
            b41 = *(const float4*)(wrow + (size_t)(k0 + BK) * NE + 4);
        }

#pragma unroll 8
        for (int kk = 0; kk < BK; ++kk) {
            double a0 = (double)As[kk][ty * 2];
            double a1 = (double)As[kk][ty * 2 + 1];
            float4 b = *(const float4*)&Bs[kk][tx * 4];
            double bv[4] = {(double)b.x, (double)b.y, (double)b.z, (double)b.w};
#pragma unroll
            for (int j = 0; j < 4; ++j) {
                acc[0][j] = fma(a0, bv[j], acc[0][j]);
                acc[1][j] = fma(a1, bv[j], acc[1][j]);
            }
        }
    }

    __syncthreads();
#pragma unroll
    for (int r = 0; r < 2; ++r)
#pragma unroll
        for (int c = 0; c < 4; ++c)
            Dm[ty * 2 + r][tx * 4 + c] = acc[r][c];
    __syncthreads();

    // ---- per-token epilogue: 4 waves x 8 tokens, lane = expert ----
    const int wave = t >> 6;
    const int lane = t & 63;
    const double b2v = (double)b2[0];

    for (int i = 0; i < 8; ++i) {
        const int tl = wave * 8 + i;
        const int token = m0 + tl;
        double g = Dm[tl][lane];

        double mx = g;
#pragma unroll
        for (int o = 32; o > 0; o >>= 1) mx = fmax(mx, __shfl_xor(mx, o, 64));
        double e = exp(g - mx);
        double s = e;
#pragma unroll
        for (int o = 32; o > 0; o >>= 1) s += __shfl_xor(s, o, 64);
        double p = e / s;

        double pv = p; int pi = lane;
        double vt[3]; int it[3];
#pragma unroll
        for (int j = 0; j < 3; ++j) {
            double v = pv; int idx = pi;
#pragma unroll
            for (int o = 32; o > 0; o >>= 1) {
                double ov = __shfl_xor(v, o, 64);
                int    oi = __shfl_xor(idx, o, 64);
                if (ov > v || (ov == v && oi < idx)) { v = ov; idx = oi; }
            }
            vt[j] = v; it[j] = idx;
            if (lane == idx) pv = -1.0;
        }

        double plv = (lane < NT) ? pl[(size_t)token * NT + lane] : 0.0;
#pragma unroll
        for (int o = 32; o > 0; o >>= 1) plv += __shfl_xor(plv, o, 64);
        double logit = plv + b2v;
        double score = 1.0 / (1.0 + exp(-logit));
        int k = (int)rint(score * 3.0) + 1;
        k = k < 1 ? 1 : (k > 3 ? 3 : k);

        double wmask[3]; double wsum = 0.0;
#pragma unroll
        for (int j = 0; j < 3; ++j) { wmask[j] = (j < k) ? vt[j] : 0.0; wsum += wmask[j]; }
        double denom = wsum + 1e-8;
        float wn[3];
#pragma unroll
        for (int j = 0; j < 3; ++j) wn[j] = (float)(wmask[j] / denom);

        float mval = 0.f;
#pragma unroll
        for (int j = 0; j < 3; ++j)
            if (it[j] == lane && wn[j] > 0.f) mval = 1.f;

        out[(size_t)6 * Ntok + (size_t)token * NE + lane] = mval;
        if (lane < 3) {
            out[(size_t)token * 3 + lane] = wn[lane];
            out[(size_t)3 * Ntok + (size_t)token * 3 + lane] = (float)it[lane];
        }
        if (lane == 0) out[(size_t)70 * Ntok + token] = (float)k;
    }
}

// ---------------------------------------------------------------------------
extern "C" void kernel_launch(void* const* d_in, const int* in_sizes, int n_in,
                              void* d_out, int out_size, void* d_ws, size_t ws_size,
                              hipStream_t stream)
{
    const float* x  = (const float*)d_in[0];
    const float* W  = (const float*)d_in[1];
    const float* W1 = (const float*)d_in[2];
    const float* b1 = (const float*)d_in[3];
    const float* W2 = (const float*)d_in[4];
    const float* b2 = (const float*)d_in[5];
    float* out = (float*)d_out;

    const int Ntok = in_sizes[0] / DD;           // 16384

    // ws layout
    double* pl = (double*)d_ws;
    const size_t pl_b   = (size_t)Ntok * NT * sizeof(double);
    const size_t o_w1h  = (pl_b + 255) & ~(size_t)255;
    const size_t w1_b   = (size_t)DD * HH * 2;           // 16 MB per plane
    const size_t o_w1l  = o_w1h + w1_b;
    const size_t o_xh   = o_w1l + w1_b;
    const size_t x_b    = (size_t)Ntok * DD * 2;         // 128 MB per plane
    const size_t o_xl   = o_xh + x_b;
    const size_t need_w1   = o_xh;                       // ~34 MB
    const size_t need_full = o_xl + x_b;                 // ~290 MB

    const bool ok128 = (Ntok % 128) == 0;

    if (ok128 && ws_size >= need_w1) {
        unsigned short* w1th = (unsigned short*)((char*)d_ws + o_w1h);
        unsigned short* w1tl = (unsigned short*)((char*)d_ws + o_w1l);
        split_w1t<<<dim3(HH / 32, DD / 32), 256, 0, stream>>>(W1, w1th, w1tl);
        if (ws_size >= need_full) {
            unsigned short* xfh = (unsigned short*)((char*)d_ws + o_xh);
            unsigned short* xfl = (unsigned short*)((char*)d_ws + o_xl);
            split_xf<<<Ntok, 256, 0, stream>>>(x, (uint4*)xfh, (uint4*)xfl);
            pred_mfma<true><<<16 * (Ntok / 128), 256, 0, stream>>>(
                x, xfh, xfl, w1th, w1tl, b1, W2, pl);
        } else {
            pred_mfma<false><<<16 * (Ntok / 128), 256, 0, stream>>>(
                x, nullptr, nullptr, w1th, w1tl, b1, W2, pl);
        }
    } else {
        pred_gemm<<<dim3(NT, Ntok / 128), 256, 0, stream>>>(x, W1, b1, W2, pl);
    }

    gate_fused<<<Ntok / GM, 256, 0, stream>>>(x, W, pl, b2, out, Ntok);
}

// Round 5
// 1549.064 us; speedup vs baseline: 1.2232x; 1.2232x over previous
//
#include <hip/hip_runtime.h>
#include <hip/hip_bf16.h>
#include <math.h>

#define DD   4096   // feature dim
#define HH   2048   // hidden dim
#define NE   64     // experts
#define BK   32
#define NT   16     // hidden tiles (HH/128)
#define GM   32     // gate token tile

typedef __attribute__((ext_vector_type(8))) short bf16x8;
typedef __attribute__((ext_vector_type(4))) float f32x4;

// async global->LDS, 16B per lane, dest = uniform base + lane*16
__device__ __forceinline__ void async16(void* lds, const void* g) {
    __builtin_amdgcn_global_load_lds(
        (const __attribute__((address_space(1))) unsigned int*)g,
        (__attribute__((address_space(3))) unsigned int*)lds, 16, 0, 0);
}

// split two floats into bf16 hi (RNE) + bf16 lo (RNE of exact residual)
__device__ __forceinline__ void split2(float a, float b, unsigned& hi, unsigned& lo) {
    __hip_bfloat162 h = __float22bfloat162_rn(make_float2(a, b));
    float2 hf = __bfloat1622float2(h);
    __hip_bfloat162 l = __float22bfloat162_rn(make_float2(a - hf.x, b - hf.y));
    __builtin_memcpy(&hi, &h, 4);
    __builtin_memcpy(&lo, &l, 4);
}

// ---------------------------------------------------------------------------
// presplit x -> hi/lo bf16 planes in MFMA FRAGMENT order:
//   chunk index = ((mt*128 + ks)*8 + fb)*64 + ln   (16B uint4 chunks)
//   holds x[row = mt*128 + fb*16 + (ln&15)][k = ks*32 + (ln>>4)*8 .. +8]
// ---------------------------------------------------------------------------
__global__ __launch_bounds__(256) void split_xf(
    const float* __restrict__ x, uint4* __restrict__ xfh, uint4* __restrict__ xfl)
{
    const int t = threadIdx.x;
    const int mt = blockIdx.x >> 7;      // token tile (128 rows)
    const int ks = blockIdx.x & 127;     // k step (32 k)
#pragma unroll
    for (int s2 = 0; s2 < 2; ++s2) {
        int s = t + s2 * 256;            // 0..511 chunk within (mt,ks)
        int fb = s >> 6, ln = s & 63;
        int row = mt * 128 + fb * 16 + (ln & 15);
        int k   = ks * 32 + (ln >> 4) * 8;
        const float* g = x + (size_t)row * DD + k;
        float4 a = *(const float4*)g, b = *(const float4*)(g + 4);
        unsigned h0, l0, h1, l1, h2, l2, h3, l3;
        split2(a.x, a.y, h0, l0); split2(a.z, a.w, h1, l1);
        split2(b.x, b.y, h2, l2); split2(b.z, b.w, h3, l3);
        size_t idx = ((size_t)blockIdx.x * 8 + fb) * 64 + ln;
        xfh[idx] = make_uint4(h0, h1, h2, h3);
        xfl[idx] = make_uint4(l0, l1, l2, l3);
    }
}

// ---------------------------------------------------------------------------
// presplit + transpose W1[K][N] -> W1t hi/lo planes [N][K]
// ---------------------------------------------------------------------------
__global__ __launch_bounds__(256) void split_w1t(
    const float* __restrict__ W1,
    unsigned short* __restrict__ th, unsigned short* __restrict__ tl)
{
    __shared__ float ts[32][33];
    const int n0 = blockIdx.x * 32, k0 = blockIdx.y * 32;
    const int t = threadIdx.x;
    {
        int r = t >> 3, c4 = (t & 7) * 4;
        float4 v = *(const float4*)&W1[(size_t)(k0 + r) * HH + n0 + c4];
        ts[r][c4] = v.x; ts[r][c4 + 1] = v.y; ts[r][c4 + 2] = v.z; ts[r][c4 + 3] = v.w;
    }
    __syncthreads();
    int n = t >> 3, kk = (t & 7) * 4;
    float f0 = ts[kk][n], f1 = ts[kk + 1][n], f2 = ts[kk + 2][n], f3 = ts[kk + 3][n];
    unsigned h0, l0, h1, l1;
    split2(f0, f1, h0, l0); split2(f2, f3, h1, l1);
    *(uint2*)&th[(size_t)(n0 + n) * DD + k0 + kk] = make_uint2(h0, h1);
    *(uint2*)&tl[(size_t)(n0 + n) * DD + k0 + kk] = make_uint2(l0, l1);
}

// ---------------------------------------------------------------------------
// K1: predictor GEMM via bf16 MFMA, 3-product hi/lo split, fp32 MFMA acc.
// 128x128 tile, BK=32. A operands direct global->VGPR from fragment-ordered
// planes (round-3 register set: NO ping-pong -> no spill).
// NEW this round (T3/T4 counted-vmcnt, m201/m218 pattern):
//  - B LDS double-buffered (2 x 16KB, still 32KB total)
//  - ONE raw s_barrier per K-step with s_waitcnt vmcnt(8) (NOT 0):
//    per-wave vmem queue at step end = [4 B-asyncs][4 ah][4 al]; vmcnt(8)
//    retires exactly the asyncs (needed for next step's ds_reads) while
//    the 8 A-loads stay in flight across the barrier. al(ks+1) gains
//    barrier+ds_read+pass1 cover (was ZERO in round 3); ah keeps pass2
//    cover. Async-issue order pinned first-in-step by sched_barrier(0).
// MFMA product order per acc element stays hh -> hl -> lh => pl bitwise
// identical to previous rounds.
// ---------------------------------------------------------------------------
template<bool PRE_A>
__global__ __launch_bounds__(256, 3) void pred_mfma(
    const float* __restrict__ x,
    const unsigned short* __restrict__ xh, const unsigned short* __restrict__ xl,
    const unsigned short* __restrict__ w1th, const unsigned short* __restrict__ w1tl,
    const float* __restrict__ b1, const float* __restrict__ W2,
    double* __restrict__ pl)
{
    __shared__ __align__(16) char lds[32768];

    const int t = threadIdx.x, wv = t >> 6, ln = t & 63;
    // XCD swizzle: consecutive lins hit distinct XCDs; ntile fast within mtile
    const int lin = blockIdx.x;
    const int sub = lin >> 3;
    const int ntile = (lin & 7) * 2 + (sub & 1);
    const int mtile = sub >> 1;
    const int m0 = mtile * 128, n0 = ntile * 128;
    const int frow = ln & 15;            // fragment row/col within 16
    const int fkb  = (ln >> 4) * 8;      // fragment k offset (8 bf16)

    f32x4 acc[4][4];
#pragma unroll
    for (int i = 0; i < 4; ++i)
#pragma unroll
        for (int j = 0; j < 4; ++j) acc[i][j] = (f32x4){0.f, 0.f, 0.f, 0.f};

    const int mb = (wv & 1) * 4, nb = (wv >> 1) * 4;

    if (PRE_A) {
        // buffer b (0/1) base: lds + b*16384; within buffer: Bh +0, Bl +8192
        // staging role: wv0 -> Bh fb0-3, wv1 -> Bh fb4-7,
        //               wv2 -> Bl fb0-3, wv3 -> Bl fb4-7
        const unsigned short* bsrc = (wv & 2) ? w1tl : w1th;
        const int roleoff = ((wv & 2) ? 8192 : 0) + (wv & 1) * 4096;
        const unsigned short* bg =
            bsrc + (size_t)(n0 + (wv & 1) * 64 + frow) * DD + fkb;

        // A fragment-plane per-lane bases (uint4 units); frag i of step ks is
        // at base + ks*512 + i*64
        const uint4* gh = (const uint4*)xh + ((size_t)mtile * 1024 + mb) * 64 + ln;
        const uint4* gl = (const uint4*)xl + ((size_t)mtile * 1024 + mb) * 64 + ln;

        bf16x8 ah[4], al[4];

        // prologue: B(0) asyncs FIRST (oldest in queue), then A(0) loads
#pragma unroll
        for (int q = 0; q < 4; ++q)
            async16(lds + roleoff + q * 1024, bg + (size_t)q * 16 * DD);
        __builtin_amdgcn_sched_barrier(0);
#pragma unroll
        for (int i = 0; i < 4; ++i) {
            ah[i] = *(const bf16x8*)(gh + i * 64);
            al[i] = *(const bf16x8*)(gl + i * 64);
        }
        // retire asyncs only (queue: 4 async + 8 A-loads -> keep 8)
        asm volatile("s_waitcnt vmcnt(8)" ::: "memory");
        __builtin_amdgcn_s_barrier();

        for (int ks = 0; ks < 128; ++ks) {
            const int rb = (ks & 1) << 14;      // read buffer base
            const int sb = rb ^ 16384;          // stage buffer base
            const bool more = (ks + 1 < 128);

            if (more) {                          // asyncs first-in-step
#pragma unroll
                for (int q = 0; q < 4; ++q)
                    async16(lds + sb + roleoff + q * 1024,
                            bg + (size_t)q * 16 * DD + (ks + 1) * BK);
            }
            __builtin_amdgcn_sched_barrier(0);   // pin: asyncs oldest

            bf16x8 bfh[4], bfl[4];
#pragma unroll
            for (int j = 0; j < 4; ++j) {
                bfh[j] = *(const bf16x8*)(lds + rb + (nb + j) * 1024 + ln * 16);
                bfl[j] = *(const bf16x8*)(lds + rb + 8192 + (nb + j) * 1024 + ln * 16);
            }

            // pass 1: hh + hl (last use of ah)
#pragma unroll
            for (int i = 0; i < 4; ++i)
#pragma unroll
                for (int j = 0; j < 4; ++j) {
                    acc[i][j] = __builtin_amdgcn_mfma_f32_16x16x32_bf16(ah[i], bfh[j], acc[i][j], 0, 0, 0);
                    acc[i][j] = __builtin_amdgcn_mfma_f32_16x16x32_bf16(ah[i], bfl[j], acc[i][j], 0, 0, 0);
                }
            if (more) {                          // reload ah after last use
#pragma unroll
                for (int i = 0; i < 4; ++i)
                    ah[i] = *(const bf16x8*)(gh + (size_t)(ks + 1) * 512 + i * 64);
            }
            // pass 2: lh (last use of al)
#pragma unroll
            for (int i = 0; i < 4; ++i)
#pragma unroll
                for (int j = 0; j < 4; ++j)
                    acc[i][j] = __builtin_amdgcn_mfma_f32_16x16x32_bf16(al[i], bfh[j], acc[i][j], 0, 0, 0);
            if (more) {                          // reload al after last use
#pragma unroll
                for (int i = 0; i < 4; ++i)
                    al[i] = *(const bf16x8*)(gl + (size_t)(ks + 1) * 512 + i * 64);
                // queue: [4 asyncs][4 ah][4 al] -> retire asyncs only,
                // A-loads stay in flight across the barrier
                asm volatile("s_waitcnt vmcnt(8)" ::: "memory");
                __builtin_amdgcn_s_barrier();
            }
        }
    } else {
        // fallback: in-kernel split of fp32 x (round-0 structure, unchanged)
        char* Ah = lds;
        char* Al = lds + 8192;
        char* Bh = lds + 16384;
        char* Bl = lds + 24576;
        const unsigned short* gBh = w1th + (size_t)(n0 + frow) * DD + fkb;
        const unsigned short* gBl = w1tl + (size_t)(n0 + frow) * DD + fkb;

        for (int kc = 0; kc < DD; kc += BK) {
#pragma unroll
            for (int q = 0; q < 2; ++q) {
                int fb = wv * 2 + q;
                async16(Bh + fb * 1024, gBh + (size_t)fb * 16 * DD + kc);
                async16(Bl + fb * 1024, gBl + (size_t)fb * 16 * DD + kc);
            }
#pragma unroll
            for (int s2 = 0; s2 < 2; ++s2) {
                int s = t + s2 * 256;
                int fb = s >> 6, sl = s & 63;
                int row = fb * 16 + (sl & 15), kb = (sl >> 4) * 8;
                const float* g = x + (size_t)(m0 + row) * DD + kc + kb;
                float4 a = *(const float4*)g, b = *(const float4*)(g + 4);
                unsigned h0, l0, h1, l1, h2, l2, h3, l3;
                split2(a.x, a.y, h0, l0); split2(a.z, a.w, h1, l1);
                split2(b.x, b.y, h2, l2); split2(b.z, b.w, h3, l3);
                *(uint4*)(Ah + s * 16) = make_uint4(h0, h1, h2, h3);
                *(uint4*)(Al + s * 16) = make_uint4(l0, l1, l2, l3);
            }
            __syncthreads();

            bf16x8 afh[4], afl[4], bfh[4], bfl[4];
#pragma unroll
            for (int i = 0; i < 4; ++i) {
                afh[i] = *(const bf16x8*)(Ah + (mb + i) * 1024 + ln * 16);
                afl[i] = *(const bf16x8*)(Al + (mb + i) * 1024 + ln * 16);
                bfh[i] = *(const bf16x8*)(Bh + (nb + i) * 1024 + ln * 16);
                bfl[i] = *(const bf16x8*)(Bl + (nb + i) * 1024 + ln * 16);
            }
#pragma unroll
            for (int i = 0; i < 4; ++i)
#pragma unroll
                for (int j = 0; j < 4; ++j) {
                    acc[i][j] = __builtin_amdgcn_mfma_f32_16x16x32_bf16(afh[i], bfh[j], acc[i][j], 0, 0, 0);
                    acc[i][j] = __builtin_amdgcn_mfma_f32_16x16x32_bf16(afh[i], bfl[j], acc[i][j], 0, 0, 0);
                    acc[i][j] = __builtin_amdgcn_mfma_f32_16x16x32_bf16(afl[i], bfh[j], acc[i][j], 0, 0, 0);
                }
            __syncthreads();
        }
    }

    // epilogue: relu(c + b1) * W2, fp64 reduction. C layout: col=ln&15,
    // row=(ln>>4)*4+r per 16x16 frag.
    __syncthreads();
    double* redd = (double*)lds;   // [2][128]
    const int mh = wv & 1, nh = wv >> 1;
    float b1v[4], w2v[4];
#pragma unroll
    for (int j = 0; j < 4; ++j) {
        int col = n0 + nh * 64 + j * 16 + frow;
        b1v[j] = b1[col];
        w2v[j] = W2[col];
    }
#pragma unroll
    for (int i = 0; i < 4; ++i)
#pragma unroll
        for (int r = 0; r < 4; ++r) {
            double s = 0.0;
#pragma unroll
            for (int j = 0; j < 4; ++j) {
                float h = acc[i][j][r] + b1v[j];
                h = fmaxf(h, 0.f);
                s += (double)h * (double)w2v[j];
            }
#pragma unroll
            for (int o = 1; o < 16; o <<= 1) s += __shfl_xor(s, o, 64);
            if (frow == 0)
                redd[nh * 128 + mh * 64 + i * 16 + (ln >> 4) * 4 + r] = s;
        }
    __syncthreads();
    if (t < 128)
        pl[(size_t)(m0 + t) * NT + ntile] = redd[t] + redd[128 + t];
}

// ---------------------------------------------------------------------------
// Fallback K1 (round-2): fp32 VALU GEMM, used only if ws is too small.
// ---------------------------------------------------------------------------
__global__ __launch_bounds__(256) void pred_gemm(
    const float* __restrict__ x, const float* __restrict__ W1,
    const float* __restrict__ b1, const float* __restrict__ W2,
    double* __restrict__ pl)
{
    __shared__ float As[BK][128];
    __shared__ float Bs[BK][128];
    __shared__ double red[128][NT + 1];

    const int ht = blockIdx.x;
    const int tm = blockIdx.y;
    const int t  = threadIdx.x;
    const int tx = t & 15, ty = t >> 4;
    const int h0 = ht * 128;
    const int m0 = tm * 128;

    float acc[8][8];
#pragma unroll
    for (int i = 0; i < 8; ++i)
#pragma unroll
        for (int j = 0; j < 8; ++j) acc[i][j] = 0.f;

    const int arow = t >> 1, acol = (t & 1) << 4;
    const int brow = t >> 3, bcol = (t & 7) << 4;
    const float* xrow = x  + (size_t)(m0 + arow) * DD + acol;
    const float* wrow = W1 + (size_t)brow * HH + h0 + bcol;

    for (int k0 = 0; k0 < DD; k0 += BK) {
        float4 a4[4], b4[4];
        const float4* ap = (const float4*)(xrow + k0);
#pragma unroll
        for (int i = 0; i < 4; ++i) a4[i] = ap[i];
        const float4* bp = (const float4*)(wrow + (size_t)k0 * HH);
#pragma unroll
        for (int i = 0; i < 4; ++i) b4[i] = bp[i];
        __syncthreads();
#pragma unroll
        for (int i = 0; i < 4; ++i) {
            As[acol + i * 4 + 0][arow] = a4[i].x;
            As[acol + i * 4 + 1][arow] = a4[i].y;
            As[acol + i * 4 + 2][arow] = a4[i].z;
            As[acol + i * 4 + 3][arow] = a4[i].w;
        }
#pragma unroll
        for (int i = 0; i < 4; ++i)
            *(float4*)&Bs[brow][bcol + i * 4] = b4[i];
        __syncthreads();
#pragma unroll 8
        for (int kk = 0; kk < BK; ++kk) {
            float4 a0  = *(const float4*)&As[kk][ty * 8];
            float4 a1  = *(const float4*)&As[kk][ty * 8 + 4];
            float4 bb0 = *(const float4*)&Bs[kk][tx * 8];
            float4 bb1 = *(const float4*)&Bs[kk][tx * 8 + 4];
            float av[8] = {a0.x, a0.y, a0.z, a0.w, a1.x, a1.y, a1.z, a1.w};
            float bv[8] = {bb0.x, bb0.y, bb0.z, bb0.w, bb1.x, bb1.y, bb1.z, bb1.w};
#pragma unroll
            for (int i = 0; i < 8; ++i)
#pragma unroll
                for (int j = 0; j < 8; ++j)
                    acc[i][j] = fmaf(av[i], bv[j], acc[i][j]);
        }
    }
    __syncthreads();
#pragma unroll
    for (int r = 0; r < 8; ++r) {
        double s = 0.0;
#pragma unroll
        for (int c = 0; c < 8; ++c) {
            int h = h0 + tx * 8 + c;
            float v = acc[r][c] + b1[h];
            v = v > 0.f ? v : 0.f;
            s += (double)v * (double)W2[h];
        }
        red[ty * 8 + r][tx] = s;
    }
    __syncthreads();
    if (t < 128) {
        double s = 0.0;
#pragma unroll
        for (int j = 0; j < NT; ++j) s += red[t][j];
        pl[(size_t)(m0 + t) * NT + ht] = s;
    }
}

// ---------------------------------------------------------------------------
// K2 (fused): fp64 gating GEMM + routing epilogue.
// Round-0 version (fastest measured): 256 thr, 2x4 tile, 32-token blocks,
// fp32 LDS tiles, register prefetch of next K-chunk. DO NOT MODIFY:
// both attempted variants (128thr/4x4, fp64-LDS) regressed ~140-200 us.
// ---------------------------------------------------------------------------
__global__ __launch_bounds__(256) void gate_fused(
    const float* __restrict__ x, const float* __restrict__ W,
    const double* __restrict__ pl, const float* __restrict__ b2,
    float* __restrict__ out, int Ntok)
{
    __shared__ __align__(16) char smem[GM * (NE + 1) * sizeof(double)]; // 16.6 KB
    float (*As)[GM] = (float(*)[GM])smem;                  // [BK][GM]  4 KB
    float (*Bs)[NE] = (float(*)[NE])(smem + BK * GM * 4);  // [BK][NE]  8 KB
    double (*Dm)[NE + 1] = (double(*)[NE + 1])smem;        // logits after GEMM

    const int tm = blockIdx.x;
    const int t  = threadIdx.x;
    const int tx = t & 15, ty = t >> 4;    // output: rows ty*2..+1, cols tx*4..+3
    const int m0 = tm * GM;

    double acc[2][4];
#pragma unroll
    for (int i = 0; i < 2; ++i)
#pragma unroll
        for (int j = 0; j < 4; ++j) acc[i][j] = 0.0;

    const int arow = t >> 3, acol = (t & 7) * 4;   // A: 32 rows x 32 k, 1 float4/thr
    const int brow = t >> 3, bcol = (t & 7) * 8;   // B: 32 k x 64,     2 float4/thr
    const float* xrow = x + (size_t)(m0 + arow) * DD + acol;
    const float* wrow = W + (size_t)brow * NE + bcol;

    // prologue: chunk-0 registers
    float4 a4  = *(const float4*)xrow;
    float4 b40 = *(const float4*)wrow;
    float4 b41 = *(const float4*)(wrow + 4);

    for (int k0 = 0; k0 < DD; k0 += BK) {
        __syncthreads();                 // previous compute done reading LDS
        As[acol + 0][arow] = a4.x;       // A transpose to k-major
        As[acol + 1][arow] = a4.y;
        As[acol + 2][arow] = a4.z;
        As[acol + 3][arow] = a4.w;
        *(float4*)&Bs[brow][bcol]     = b40;
        *(float4*)&Bs[brow][bcol + 4] = b41;
        __syncthreads();

        if (k0 + BK < DD) {              // prefetch next chunk into registers
            a4  = *(const float4*)(xrow + k0 + BK);
            b40 = *(const float4*)(wrow + (size_t)(k0 + BK) * NE);
            b41 = *(const float4*)(wrow + (size_t)(k0 + BK) * NE + 4);
        }

#pragma unroll 8
        for (int kk = 0; kk < BK; ++kk) {
            double a0 = (double)As[kk][ty * 2];
            double a1 = (double)As[kk][ty * 2 + 1];
            float4 b = *(const float4*)&Bs[kk][tx * 4];
            double bv[4] = {(double)b.x, (double)b.y, (double)b.z, (double)b.w};
#pragma unroll
            for (int j = 0; j < 4; ++j) {
                acc[0][j] = fma(a0, bv[j], acc[0][j]);
                acc[1][j] = fma(a1, bv[j], acc[1][j]);
            }
        }
    }

    __syncthreads();
#pragma unroll
    for (int r = 0; r < 2; ++r)
#pragma unroll
        for (int c = 0; c < 4; ++c)
            Dm[ty * 2 + r][tx * 4 + c] = acc[r][c];
    __syncthreads();

    // ---- per-token epilogue: 4 waves x 8 tokens, lane = expert ----
    const int wave = t >> 6;
    const int lane = t & 63;
    const double b2v = (double)b2[0];

    for (int i = 0; i < 8; ++i) {
        const int tl = wave * 8 + i;
        const int token = m0 + tl;
        double g = Dm[tl][lane];

        double mx = g;
#pragma unroll
        for (int o = 32; o > 0; o >>= 1) mx = fmax(mx, __shfl_xor(mx, o, 64));
        double e = exp(g - mx);
        double s = e;
#pragma unroll
        for (int o = 32; o > 0; o >>= 1) s += __shfl_xor(s, o, 64);
        double p = e / s;

        double pv = p; int pi = lane;
        double vt[3]; int it[3];
#pragma unroll
        for (int j = 0; j < 3; ++j) {
            double v = pv; int idx = pi;
#pragma unroll
            for (int o = 32; o > 0; o >>= 1) {
                double ov = __shfl_xor(v, o, 64);
                int    oi = __shfl_xor(idx, o, 64);
                if (ov > v || (ov == v && oi < idx)) { v = ov; idx = oi; }
            }
            vt[j] = v; it[j] = idx;
            if (lane == idx) pv = -1.0;
        }

        double plv = (lane < NT) ? pl[(size_t)token * NT + lane] : 0.0;
#pragma unroll
        for (int o = 32; o > 0; o >>= 1) plv += __shfl_xor(plv, o, 64);
        double logit = plv + b2v;
        double score = 1.0 / (1.0 + exp(-logit));
        int k = (int)rint(score * 3.0) + 1;
        k = k < 1 ? 1 : (k > 3 ? 3 : k);

        double wmask[3]; double wsum = 0.0;
#pragma unroll
        for (int j = 0; j < 3; ++j) { wmask[j] = (j < k) ? vt[j] : 0.0; wsum += wmask[j]; }
        double denom = wsum + 1e-8;
        float wn[3];
#pragma unroll
        for (int j = 0; j < 3; ++j) wn[j] = (float)(wmask[j] / denom);

        float mval = 0.f;
#pragma unroll
        for (int j = 0; j < 3; ++j)
            if (it[j] == lane && wn[j] > 0.f) mval = 1.f;

        out[(size_t)6 * Ntok + (size_t)token * NE + lane] = mval;
        if (lane < 3) {
            out[(size_t)token * 3 + lane] = wn[lane];
            out[(size_t)3 * Ntok + (size_t)token * 3 + lane] = (float)it[lane];
        }
        if (lane == 0) out[(size_t)70 * Ntok + token] = (float)k;
    }
}

// ---------------------------------------------------------------------------
extern "C" void kernel_launch(void* const* d_in, const int* in_sizes, int n_in,
                              void* d_out, int out_size, void* d_ws, size_t ws_size,
                              hipStream_t stream)
{
    const float* x  = (const float*)d_in[0];
    const float* W  = (const float*)d_in[1];
    const float* W1 = (const float*)d_in[2];
    const float* b1 = (const float*)d_in[3];
    const float* W2 = (const float*)d_in[4];
    const float* b2 = (const float*)d_in[5];
    float* out = (float*)d_out;

    const int Ntok = in_sizes[0] / DD;           // 16384

    // ws layout
    double* pl = (double*)d_ws;
    const size_t pl_b   = (size_t)Ntok * NT * sizeof(double);
    const size_t o_w1h  = (pl_b + 255) & ~(size_t)255;
    const size_t w1_b   = (size_t)DD * HH * 2;           // 16 MB per plane
    const size_t o_w1l  = o_w1h + w1_b;
    const size_t o_xh   = o_w1l + w1_b;
    const size_t x_b    = (size_t)Ntok * DD * 2;         // 128 MB per plane
    const size_t o_xl   = o_xh + x_b;
    const size_t need_w1   = o_xh;                       // ~34 MB
    const size_t need_full = o_xl + x_b;                 // ~290 MB

    const bool ok128 = (Ntok % 128) == 0;

    if (ok128 && ws_size >= need_w1) {
        unsigned short* w1th = (unsigned short*)((char*)d_ws + o_w1h);
        unsigned short* w1tl = (unsigned short*)((char*)d_ws + o_w1l);
        split_w1t<<<dim3(HH / 32, DD / 32), 256, 0, stream>>>(W1, w1th, w1tl);
        if (ws_size >= need_full) {
            unsigned short* xfh = (unsigned short*)((char*)d_ws + o_xh);
            unsigned short* xfl = (unsigned short*)((char*)d_ws + o_xl);
            split_xf<<<Ntok, 256, 0, stream>>>(x, (uint4*)xfh, (uint4*)xfl);
            pred_mfma<true><<<16 * (Ntok / 128), 256, 0, stream>>>(
                x, xfh, xfl, w1th, w1tl, b1, W2, pl);
        } else {
            pred_mfma<false><<<16 * (Ntok / 128), 256, 0, stream>>>(
                x, nullptr, nullptr, w1th, w1tl, b1, W2, pl);
        }
    } else {
        pred_gemm<<<dim3(NT, Ntok / 128), 256, 0, stream>>>(x, W1, b1, W2, pl);
    }

    gate_fused<<<Ntok / GM, 256, 0, stream>>>(x, W, pl, b2, out, Ntok);
}

// Round 6
// 1477.140 us; speedup vs baseline: 1.2828x; 1.0487x over previous
//
#include <hip/hip_runtime.h>
#include <hip/hip_bf16.h>
#include <math.h>

#define DD   4096   // feature dim
#define HH   2048   // hidden dim
#define NE   64     // experts
#define BK   32
#define NT   16     // hidden tiles (HH/128)
#define GM   32     // gate token tile

typedef __attribute__((ext_vector_type(8))) short bf16x8;
typedef __attribute__((ext_vector_type(4))) float f32x4;

// async global->LDS, 16B per lane, dest = uniform base + lane*16
__device__ __forceinline__ void async16(void* lds, const void* g) {
    __builtin_amdgcn_global_load_lds(
        (const __attribute__((address_space(1))) unsigned int*)g,
        (__attribute__((address_space(3))) unsigned int*)lds, 16, 0, 0);
}

// split two floats into bf16 hi (RNE) + bf16 lo (RNE of exact residual)
__device__ __forceinline__ void split2(float a, float b, unsigned& hi, unsigned& lo) {
    __hip_bfloat162 h = __float22bfloat162_rn(make_float2(a, b));
    float2 hf = __bfloat1622float2(h);
    __hip_bfloat162 l = __float22bfloat162_rn(make_float2(a - hf.x, b - hf.y));
    __builtin_memcpy(&hi, &h, 4);
    __builtin_memcpy(&lo, &l, 4);
}

// ---------------------------------------------------------------------------
// presplit x -> hi/lo bf16 planes in MFMA FRAGMENT order:
//   chunk index = ((mt*128 + ks)*8 + fb)*64 + ln   (16B uint4 chunks)
//   holds x[row = mt*128 + fb*16 + (ln&15)][k = ks*32 + (ln>>4)*8 .. +8]
// ---------------------------------------------------------------------------
__global__ __launch_bounds__(256) void split_xf(
    const float* __restrict__ x, uint4* __restrict__ xfh, uint4* __restrict__ xfl)
{
    const int t = threadIdx.x;
    const int mt = blockIdx.x >> 7;      // token tile (128 rows)
    const int ks = blockIdx.x & 127;     // k step (32 k)
#pragma unroll
    for (int s2 = 0; s2 < 2; ++s2) {
        int s = t + s2 * 256;            // 0..511 chunk within (mt,ks)
        int fb = s >> 6, ln = s & 63;
        int row = mt * 128 + fb * 16 + (ln & 15);
        int k   = ks * 32 + (ln >> 4) * 8;
        const float* g = x + (size_t)row * DD + k;
        float4 a = *(const float4*)g, b = *(const float4*)(g + 4);
        unsigned h0, l0, h1, l1, h2, l2, h3, l3;
        split2(a.x, a.y, h0, l0); split2(a.z, a.w, h1, l1);
        split2(b.x, b.y, h2, l2); split2(b.z, b.w, h3, l3);
        size_t idx = ((size_t)blockIdx.x * 8 + fb) * 64 + ln;
        xfh[idx] = make_uint4(h0, h1, h2, h3);
        xfl[idx] = make_uint4(l0, l1, l2, l3);
    }
}

// ---------------------------------------------------------------------------
// presplit + transpose W1[K][N] -> W1t hi/lo planes [N][K]
// ---------------------------------------------------------------------------
__global__ __launch_bounds__(256) void split_w1t(
    const float* __restrict__ W1,
    unsigned short* __restrict__ th, unsigned short* __restrict__ tl)
{
    __shared__ float ts[32][33];
    const int n0 = blockIdx.x * 32, k0 = blockIdx.y * 32;
    const int t = threadIdx.x;
    {
        int r = t >> 3, c4 = (t & 7) * 4;
        float4 v = *(const float4*)&W1[(size_t)(k0 + r) * HH + n0 + c4];
        ts[r][c4] = v.x; ts[r][c4 + 1] = v.y; ts[r][c4 + 2] = v.z; ts[r][c4 + 3] = v.w;
    }
    __syncthreads();
    int n = t >> 3, kk = (t & 7) * 4;
    float f0 = ts[kk][n], f1 = ts[kk + 1][n], f2 = ts[kk + 2][n], f3 = ts[kk + 3][n];
    unsigned h0, l0, h1, l1;
    split2(f0, f1, h0, l0); split2(f2, f3, h1, l1);
    *(uint2*)&th[(size_t)(n0 + n) * DD + k0 + kk] = make_uint2(h0, h1);
    *(uint2*)&tl[(size_t)(n0 + n) * DD + k0 + kk] = make_uint2(l0, l1);
}

// ---------------------------------------------------------------------------
// K1: predictor GEMM via bf16 MFMA, 3-product hi/lo split, fp32 MFMA acc.
// 128x128 tile, BK=32. Round-5 counted-vmcnt schedule KEPT (B double-buffer,
// one s_barrier per step, asyncs pinned first, A-loads stay in flight).
// NEW this round: wave grid 2x2 -> 4x1. Each wave owns 2 m-frags x ALL 8
// n-frags (acc[2][8], still 16 f32x4):
//  - A global traffic per block-step 32KB -> 16KB (no cross-wave duplicate
//    reads; waves {0,2},{1,3} previously fetched identical A frags). Per-CU
//    L2 demand drops ~62 -> ~42 B/cyc (under the ~56 B/cyc ceiling).
//  - B ds_reads 8 -> 16/wave, processed in two j-halves of 4 so B-register
//    live set stays 32 regs (total live slightly LOWER than round 5).
//  - vmcnt queue at barrier = [4 asyncs][2 ah][2 al] -> s_waitcnt vmcnt(4).
//  - epilogue: wave holds all 128 cols of its rows -> row-sum completes
//    in-wave (16-lane shuffle), pl written directly, no LDS/barrier.
// MFMA product order per acc element stays hh -> hl -> lh => GEMM bitwise
// identical; epilogue fp64 sum is one 8-term chain (last-ulp-only change
// in pl, far below any k-decision boundary).
// ---------------------------------------------------------------------------
__global__ __launch_bounds__(256, 3) void pred_mfma(
    const unsigned short* __restrict__ xh, const unsigned short* __restrict__ xl,
    const unsigned short* __restrict__ w1th, const unsigned short* __restrict__ w1tl,
    const float* __restrict__ b1, const float* __restrict__ W2,
    double* __restrict__ pl)
{
    __shared__ __align__(16) char lds[32768];

    const int t = threadIdx.x, wv = t >> 6, ln = t & 63;
    // XCD swizzle: consecutive lins hit distinct XCDs; ntile fast within mtile
    const int lin = blockIdx.x;
    const int sub = lin >> 3;
    const int ntile = (lin & 7) * 2 + (sub & 1);
    const int mtile = sub >> 1;
    const int m0 = mtile * 128, n0 = ntile * 128;
    const int frow = ln & 15;            // fragment row/col within 16
    const int fkb  = (ln >> 4) * 8;      // fragment k offset (8 bf16)

    f32x4 acc[2][8];
#pragma unroll
    for (int i = 0; i < 2; ++i)
#pragma unroll
        for (int j = 0; j < 8; ++j) acc[i][j] = (f32x4){0.f, 0.f, 0.f, 0.f};

    // B staging roles (unchanged): wv0 -> Bh fb0-3, wv1 -> Bh fb4-7,
    //                              wv2 -> Bl fb0-3, wv3 -> Bl fb4-7
    const unsigned short* bsrc = (wv & 2) ? w1tl : w1th;
    const int roleoff = ((wv & 2) ? 8192 : 0) + (wv & 1) * 4096;
    const unsigned short* bg =
        bsrc + (size_t)(n0 + (wv & 1) * 64 + frow) * DD + fkb;

    // A fragment-plane per-lane bases (uint4 units); wave owns fb = wv*2 + i
    const uint4* gh = (const uint4*)xh + ((size_t)mtile * 1024 + wv * 2) * 64 + ln;
    const uint4* gl = (const uint4*)xl + ((size_t)mtile * 1024 + wv * 2) * 64 + ln;

    bf16x8 ah[2], al[2];

    // prologue: B(0) asyncs FIRST (oldest in queue), then A(0) loads
#pragma unroll
    for (int q = 0; q < 4; ++q)
        async16(lds + roleoff + q * 1024, bg + (size_t)q * 16 * DD);
    __builtin_amdgcn_sched_barrier(0);
#pragma unroll
    for (int i = 0; i < 2; ++i) {
        ah[i] = *(const bf16x8*)(gh + i * 64);
        al[i] = *(const bf16x8*)(gl + i * 64);
    }
    // retire asyncs only (queue: 4 async + 4 A-loads -> keep 4)
    asm volatile("s_waitcnt vmcnt(4)" ::: "memory");
    __builtin_amdgcn_s_barrier();

    for (int ks = 0; ks < 128; ++ks) {
        const int rb = (ks & 1) << 14;      // read buffer base
        const int sb = rb ^ 16384;          // stage buffer base
        const bool more = (ks + 1 < 128);

        if (more) {                          // asyncs first-in-step
#pragma unroll
            for (int q = 0; q < 4; ++q)
                async16(lds + sb + roleoff + q * 1024,
                        bg + (size_t)q * 16 * DD + (ks + 1) * BK);
        }
        __builtin_amdgcn_sched_barrier(0);   // pin: asyncs oldest

        // ---- j-half 0 (n-frags 0..3) ----
        {
            bf16x8 bfh[4], bfl[4];
#pragma unroll
            for (int j = 0; j < 4; ++j) {
                bfh[j] = *(const bf16x8*)(lds + rb + j * 1024 + ln * 16);
                bfl[j] = *(const bf16x8*)(lds + rb + 8192 + j * 1024 + ln * 16);
            }
#pragma unroll
            for (int i = 0; i < 2; ++i)
#pragma unroll
                for (int j = 0; j < 4; ++j) {
                    acc[i][j] = __builtin_amdgcn_mfma_f32_16x16x32_bf16(ah[i], bfh[j], acc[i][j], 0, 0, 0);
                    acc[i][j] = __builtin_amdgcn_mfma_f32_16x16x32_bf16(ah[i], bfl[j], acc[i][j], 0, 0, 0);
                }
#pragma unroll
            for (int i = 0; i < 2; ++i)
#pragma unroll
                for (int j = 0; j < 4; ++j)
                    acc[i][j] = __builtin_amdgcn_mfma_f32_16x16x32_bf16(al[i], bfh[j], acc[i][j], 0, 0, 0);
        }

        // ---- j-half 1 (n-frags 4..7) ----
        {
            bf16x8 bfh[4], bfl[4];
#pragma unroll
            for (int j = 0; j < 4; ++j) {
                bfh[j] = *(const bf16x8*)(lds + rb + (4 + j) * 1024 + ln * 16);
                bfl[j] = *(const bf16x8*)(lds + rb + 8192 + (4 + j) * 1024 + ln * 16);
            }
#pragma unroll
            for (int i = 0; i < 2; ++i)
#pragma unroll
                for (int j = 0; j < 4; ++j) {
                    acc[i][4 + j] = __builtin_amdgcn_mfma_f32_16x16x32_bf16(ah[i], bfh[j], acc[i][4 + j], 0, 0, 0);
                    acc[i][4 + j] = __builtin_amdgcn_mfma_f32_16x16x32_bf16(ah[i], bfl[j], acc[i][4 + j], 0, 0, 0);
                }
            if (more) {                      // reload ah after last use
#pragma unroll
                for (int i = 0; i < 2; ++i)
                    ah[i] = *(const bf16x8*)(gh + (size_t)(ks + 1) * 512 + i * 64);
            }
#pragma unroll
            for (int i = 0; i < 2; ++i)
#pragma unroll
                for (int j = 0; j < 4; ++j)
                    acc[i][4 + j] = __builtin_amdgcn_mfma_f32_16x16x32_bf16(al[i], bfh[j], acc[i][4 + j], 0, 0, 0);
        }

        if (more) {                          // reload al after last use
#pragma unroll
            for (int i = 0; i < 2; ++i)
                al[i] = *(const bf16x8*)(gl + (size_t)(ks + 1) * 512 + i * 64);
            // queue: [4 asyncs][2 ah][2 al] -> retire asyncs only,
            // A-loads stay in flight across the barrier
            asm volatile("s_waitcnt vmcnt(4)" ::: "memory");
            __builtin_amdgcn_s_barrier();
        }
    }

    // epilogue: relu(c + b1) * W2, fp64 row-sum fully in-wave.
    // C frag layout: col = frow, row = (ln>>4)*4 + r. Wave wv owns rows
    // (wv*2+i)*16 + (ln>>4)*4 + r and all cols n0 + j*16 + frow.
    float b1v[8], w2v[8];
#pragma unroll
    for (int j = 0; j < 8; ++j) {
        int col = n0 + j * 16 + frow;
        b1v[j] = b1[col];
        w2v[j] = W2[col];
    }
#pragma unroll
    for (int i = 0; i < 2; ++i)
#pragma unroll
        for (int r = 0; r < 4; ++r) {
            double s = 0.0;
#pragma unroll
            for (int j = 0; j < 8; ++j) {
                float h = acc[i][j][r] + b1v[j];
                h = fmaxf(h, 0.f);
                s += (double)h * (double)w2v[j];
            }
#pragma unroll
            for (int o = 1; o < 16; o <<= 1) s += __shfl_xor(s, o, 64);
            if (frow == 0) {
                int row = m0 + (wv * 2 + i) * 16 + (ln >> 4) * 4 + r;
                pl[(size_t)row * NT + ntile] = s;
            }
        }
}

// ---------------------------------------------------------------------------
// Fallback K1: fp32 VALU GEMM, used only if ws is too small for the planes.
// ---------------------------------------------------------------------------
__global__ __launch_bounds__(256) void pred_gemm(
    const float* __restrict__ x, const float* __restrict__ W1,
    const float* __restrict__ b1, const float* __restrict__ W2,
    double* __restrict__ pl)
{
    __shared__ float As[BK][128];
    __shared__ float Bs[BK][128];
    __shared__ double red[128][NT + 1];

    const int ht = blockIdx.x;
    const int tm = blockIdx.y;
    const int t  = threadIdx.x;
    const int tx = t & 15, ty = t >> 4;
    const int h0 = ht * 128;
    const int m0 = tm * 128;

    float acc[8][8];
#pragma unroll
    for (int i = 0; i < 8; ++i)
#pragma unroll
        for (int j = 0; j < 8; ++j) acc[i][j] = 0.f;

    const int arow = t >> 1, acol = (t & 1) << 4;
    const int brow = t >> 3, bcol = (t & 7) << 4;
    const float* xrow = x  + (size_t)(m0 + arow) * DD + acol;
    const float* wrow = W1 + (size_t)brow * HH + h0 + bcol;

    for (int k0 = 0; k0 < DD; k0 += BK) {
        float4 a4[4], b4[4];
        const float4* ap = (const float4*)(xrow + k0);
#pragma unroll
        for (int i = 0; i < 4; ++i) a4[i] = ap[i];
        const float4* bp = (const float4*)(wrow + (size_t)k0 * HH);
#pragma unroll
        for (int i = 0; i < 4; ++i) b4[i] = bp[i];
        __syncthreads();
#pragma unroll
        for (int i = 0; i < 4; ++i) {
            As[acol + i * 4 + 0][arow] = a4[i].x;
            As[acol + i * 4 + 1][arow] = a4[i].y;
            As[acol + i * 4 + 2][arow] = a4[i].z;
            As[acol + i * 4 + 3][arow] = a4[i].w;
        }
#pragma unroll
        for (int i = 0; i < 4; ++i)
            *(float4*)&Bs[brow][bcol + i * 4] = b4[i];
        __syncthreads();
#pragma unroll 8
        for (int kk = 0; kk < BK; ++kk) {
            float4 a0  = *(const float4*)&As[kk][ty * 8];
            float4 a1  = *(const float4*)&As[kk][ty * 8 + 4];
            float4 bb0 = *(const float4*)&Bs[kk][tx * 8];
            float4 bb1 = *(const float4*)&Bs[kk][tx * 8 + 4];
            float av[8] = {a0.x, a0.y, a0.z, a0.w, a1.x, a1.y, a1.z, a1.w};
            float bv[8] = {bb0.x, bb0.y, bb0.z, bb0.w, bb1.x, bb1.y, bb1.z, bb1.w};
#pragma unroll
            for (int i = 0; i < 8; ++i)
#pragma unroll
                for (int j = 0; j < 8; ++j)
                    acc[i][j] = fmaf(av[i], bv[j], acc[i][j]);
        }
    }
    __syncthreads();
#pragma unroll
    for (int r = 0; r < 8; ++r) {
        double s = 0.0;
#pragma unroll
        for (int c = 0; c < 8; ++c) {
            int h = h0 + tx * 8 + c;
            float v = acc[r][c] + b1[h];
            v = v > 0.f ? v : 0.f;
            s += (double)v * (double)W2[h];
        }
        red[ty * 8 + r][tx] = s;
    }
    __syncthreads();
    if (t < 128) {
        double s = 0.0;
#pragma unroll
        for (int j = 0; j < NT; ++j) s += red[t][j];
        pl[(size_t)(m0 + t) * NT + ht] = s;
    }
}

// ---------------------------------------------------------------------------
// K2 (fused): fp64 gating GEMM + routing epilogue.
// Round-0 version (fastest measured): 256 thr, 2x4 tile, 32-token blocks,
// fp32 LDS tiles, register prefetch of next K-chunk. DO NOT MODIFY:
// both attempted variants (128thr/4x4, fp64-LDS) regressed ~140-200 us.
// ---------------------------------------------------------------------------
__global__ __launch_bounds__(256) void gate_fused(
    const float* __restrict__ x, const float* __restrict__ W,
    const double* __restrict__ pl, const float* __restrict__ b2,
    float* __restrict__ out, int Ntok)
{
    __shared__ __align__(16) char smem[GM * (NE + 1) * sizeof(double)]; // 16.6 KB
    float (*As)[GM] = (float(*)[GM])smem;                  // [BK][GM]  4 KB
    float (*Bs)[NE] = (float(*)[NE])(smem + BK * GM * 4);  // [BK][NE]  8 KB
    double (*Dm)[NE + 1] = (double(*)[NE + 1])smem;        // logits after GEMM

    const int tm = blockIdx.x;
    const int t  = threadIdx.x;
    const int tx = t & 15, ty = t >> 4;    // output: rows ty*2..+1, cols tx*4..+3
    const int m0 = tm * GM;

    double acc[2][4];
#pragma unroll
    for (int i = 0; i < 2; ++i)
#pragma unroll
        for (int j = 0; j < 4; ++j) acc[i][j] = 0.0;

    const int arow = t >> 3, acol = (t & 7) * 4;   // A: 32 rows x 32 k, 1 float4/thr
    const int brow = t >> 3, bcol = (t & 7) * 8;   // B: 32 k x 64,     2 float4/thr
    const float* xrow = x + (size_t)(m0 + arow) * DD + acol;
    const float* wrow = W + (size_t)brow * NE + bcol;

    // prologue: chunk-0 registers
    float4 a4  = *(const float4*)xrow;
    float4 b40 = *(const float4*)wrow;
    float4 b41 = *(const float4*)(wrow + 4);

    for (int k0 = 0; k0 < DD; k0 += BK) {
        __syncthreads();                 // previous compute done reading LDS
        As[acol + 0][arow] = a4.x;       // A transpose to k-major
        As[acol + 1][arow] = a4.y;
        As[acol + 2][arow] = a4.z;
        As[acol + 3][arow] = a4.w;
        *(float4*)&Bs[brow][bcol]     = b40;
        *(float4*)&Bs[brow][bcol + 4] = b41;
        __syncthreads();

        if (k0 + BK < DD) {              // prefetch next chunk into registers
            a4  = *(const float4*)(xrow + k0 + BK);
            b40 = *(const float4*)(wrow + (size_t)(k0 + BK) * NE);
            b41 = *(const float4*)(wrow + (size_t)(k0 + BK) * NE + 4);
        }

#pragma unroll 8
        for (int kk = 0; kk < BK; ++kk) {
            double a0 = (double)As[kk][ty * 2];
            double a1 = (double)As[kk][ty * 2 + 1];
            float4 b = *(const float4*)&Bs[kk][tx * 4];
            double bv[4] = {(double)b.x, (double)b.y, (double)b.z, (double)b.w};
#pragma unroll
            for (int j = 0; j < 4; ++j) {
                acc[0][j] = fma(a0, bv[j], acc[0][j]);
                acc[1][j] = fma(a1, bv[j], acc[1][j]);
            }
        }
    }

    __syncthreads();
#pragma unroll
    for (int r = 0; r < 2; ++r)
#pragma unroll
        for (int c = 0; c < 4; ++c)
            Dm[ty * 2 + r][tx * 4 + c] = acc[r][c];
    __syncthreads();

    // ---- per-token epilogue: 4 waves x 8 tokens, lane = expert ----
    const int wave = t >> 6;
    const int lane = t & 63;
    const double b2v = (double)b2[0];

    for (int i = 0; i < 8; ++i) {
        const int tl = wave * 8 + i;
        const int token = m0 + tl;
        double g = Dm[tl][lane];

        double mx = g;
#pragma unroll
        for (int o = 32; o > 0; o >>= 1) mx = fmax(mx, __shfl_xor(mx, o, 64));
        double e = exp(g - mx);
        double s = e;
#pragma unroll
        for (int o = 32; o > 0; o >>= 1) s += __shfl_xor(s, o, 64);
        double p = e / s;

        double pv = p; int pi = lane;
        double vt[3]; int it[3];
#pragma unroll
        for (int j = 0; j < 3; ++j) {
            double v = pv; int idx = pi;
#pragma unroll
            for (int o = 32; o > 0; o >>= 1) {
                double ov = __shfl_xor(v, o, 64);
                int    oi = __shfl_xor(idx, o, 64);
                if (ov > v || (ov == v && oi < idx)) { v = ov; idx = oi; }
            }
            vt[j] = v; it[j] = idx;
            if (lane == idx) pv = -1.0;
        }

        double plv = (lane < NT) ? pl[(size_t)token * NT + lane] : 0.0;
#pragma unroll
        for (int o = 32; o > 0; o >>= 1) plv += __shfl_xor(plv, o, 64);
        double logit = plv + b2v;
        double score = 1.0 / (1.0 + exp(-logit));
        int k = (int)rint(score * 3.0) + 1;
        k = k < 1 ? 1 : (k > 3 ? 3 : k);

        double wmask[3]; double wsum = 0.0;
#pragma unroll
        for (int j = 0; j < 3; ++j) { wmask[j] = (j < k) ? vt[j] : 0.0; wsum += wmask[j]; }
        double denom = wsum + 1e-8;
        float wn[3];
#pragma unroll
        for (int j = 0; j < 3; ++j) wn[j] = (float)(wmask[j] / denom);

        float mval = 0.f;
#pragma unroll
        for (int j = 0; j < 3; ++j)
            if (it[j] == lane && wn[j] > 0.f) mval = 1.f;

        out[(size_t)6 * Ntok + (size_t)token * NE + lane] = mval;
        if (lane < 3) {
            out[(size_t)token * 3 + lane] = wn[lane];
            out[(size_t)3 * Ntok + (size_t)token * 3 + lane] = (float)it[lane];
        }
        if (lane == 0) out[(size_t)70 * Ntok + token] = (float)k;
    }
}

// ---------------------------------------------------------------------------
extern "C" void kernel_launch(void* const* d_in, const int* in_sizes, int n_in,
                              void* d_out, int out_size, void* d_ws, size_t ws_size,
                              hipStream_t stream)
{
    const float* x  = (const float*)d_in[0];
    const float* W  = (const float*)d_in[1];
    const float* W1 = (const float*)d_in[2];
    const float* b1 = (const float*)d_in[3];
    const float* W2 = (const float*)d_in[4];
    const float* b2 = (const float*)d_in[5];
    float* out = (float*)d_out;

    const int Ntok = in_sizes[0] / DD;           // 16384

    // ws layout
    double* pl = (double*)d_ws;
    const size_t pl_b   = (size_t)Ntok * NT * sizeof(double);
    const size_t o_w1h  = (pl_b + 255) & ~(size_t)255;
    const size_t w1_b   = (size_t)DD * HH * 2;           // 16 MB per plane
    const size_t o_w1l  = o_w1h + w1_b;
    const size_t o_xh   = o_w1l + w1_b;
    const size_t x_b    = (size_t)Ntok * DD * 2;         // 128 MB per plane
    const size_t o_xl   = o_xh + x_b;
    const size_t need_full = o_xl + x_b;                 // ~290 MB

    const bool ok128 = (Ntok % 128) == 0;

    if (ok128 && ws_size >= need_full) {
        unsigned short* w1th = (unsigned short*)((char*)d_ws + o_w1h);
        unsigned short* w1tl = (unsigned short*)((char*)d_ws + o_w1l);
        unsigned short* xfh  = (unsigned short*)((char*)d_ws + o_xh);
        unsigned short* xfl  = (unsigned short*)((char*)d_ws + o_xl);
        split_w1t<<<dim3(HH / 32, DD / 32), 256, 0, stream>>>(W1, w1th, w1tl);
        split_xf<<<Ntok, 256, 0, stream>>>(x, (uint4*)xfh, (uint4*)xfl);
        pred_mfma<<<16 * (Ntok / 128), 256, 0, stream>>>(
            xfh, xfl, w1th, w1tl, b1, W2, pl);
    } else {
        pred_gemm<<<dim3(NT, Ntok / 128), 256, 0, stream>>>(x, W1, b1, W2, pl);
    }

    gate_fused<<<Ntok / GM, 256, 0, stream>>>(x, W, pl, b2, out, Ntok);
}